// Round 1
// baseline (352.693 us; speedup 1.0000x reference)
//
#include <hip/hip_runtime.h>
#include <stdint.h>

typedef unsigned short u16;
typedef __bf16 bf16x8 __attribute__((ext_vector_type(8)));
typedef float f32x4 __attribute__((ext_vector_type(4)));

#define INV_SCALE (19.5f/1024.0f)   // exact in binary: 39/2048

__device__ __forceinline__ u16 f2bf(float f){
  uint32_t u = __float_as_uint(f);
  return (u16)((u + 0x7FFFu + ((u >> 16) & 1u)) >> 16);   // RNE
}

#define GLD_LDS16(g,l) __builtin_amdgcn_global_load_lds( \
    (const __attribute__((address_space(1))) void*)(g),  \
    (__attribute__((address_space(3))) void*)(l), 16, 0, 0)

// ---------------- fp32 -> bf16 convert (vectorized x4) ----------------
__global__ __launch_bounds__(256) void k_cvt(const float4* __restrict__ s,
                                             uint64_t* __restrict__ d, int n4){
  int i = blockIdx.x * 256 + threadIdx.x;
  const int stride = gridDim.x * 256;
  for (; i < n4; i += stride){
    float4 f = s[i];
    union{ u16 u[4]; uint64_t v; } pk;
    pk.u[0]=f2bf(f.x); pk.u[1]=f2bf(f.y); pk.u[2]=f2bf(f.z); pk.u[3]=f2bf(f.w);
    d[i] = pk.v;
  }
}

// ---------------- 128x128 bf16 GEMM: C = A[M][1024] * Bw[Nout][1024]^T + bias ----------------
// MODE 0: QKV projection -> scatter bf16 into Q/K/V [b,h,n,dh]
// MODE 1: output projection -> fp32 C
template<int MODE>
__global__ __launch_bounds__(256) void gemm_bt(
    const u16* __restrict__ A, const u16* __restrict__ Bw,
    const float* __restrict__ bias, float* __restrict__ Cout,
    u16* __restrict__ q_ws, u16* __restrict__ k_ws, u16* __restrict__ v_ws)
{
  __shared__ u16 As[128*32];
  __shared__ u16 Bs[128*32];
  const int tid  = threadIdx.x;
  const int w    = tid >> 6, lane = tid & 63;
  const int wr   = w >> 1,  wc   = w & 1;
  const int g    = lane >> 4, c16 = lane & 15;
  const int nt   = blockIdx.x, mt = blockIdx.y;
  const size_t arow0 = (size_t)mt * 128, brow0 = (size_t)nt * 128;

  f32x4 acc[4][4] = {};

  const int srow = lane >> 2;          // row within 16-row chunk
  const int scol = (lane & 3) * 8;     // bf16-element offset within 32-wide row

  for (int k0 = 0; k0 < 1024; k0 += 32){
    __syncthreads();
    #pragma unroll
    for (int t = 0; t < 2; t++){
      const int c = w*2 + t;           // 8 chunks of 16 rows
      GLD_LDS16(A  + (arow0 + c*16 + srow)*1024 + k0 + scol, As + c*512);
      GLD_LDS16(Bw + (brow0 + c*16 + srow)*1024 + k0 + scol, Bs + c*512);
    }
    __syncthreads();

    bf16x8 af[4], bfr[4];
    #pragma unroll
    for (int m = 0; m < 4; m++)
      af[m]  = __builtin_bit_cast(bf16x8, *(const uint4*)(As + (wr*64 + m*16 + c16)*32 + g*8));
    #pragma unroll
    for (int n = 0; n < 4; n++)
      bfr[n] = __builtin_bit_cast(bf16x8, *(const uint4*)(Bs + (wc*64 + n*16 + c16)*32 + g*8));
    #pragma unroll
    for (int m = 0; m < 4; m++)
      #pragma unroll
      for (int n = 0; n < 4; n++)
        acc[m][n] = __builtin_amdgcn_mfma_f32_16x16x32_bf16(af[m], bfr[n], acc[m][n], 0, 0, 0);
  }

  #pragma unroll
  for (int m = 0; m < 4; m++){
    const size_t i0 = arow0 + wr*64 + m*16 + g*4;   // C/D: row=(lane>>4)*4+reg
    #pragma unroll
    for (int n = 0; n < 4; n++){
      const int o = (int)brow0 + wc*64 + n*16 + c16; // C/D: col=lane&15
      const float bias_v = bias[o];
      if (MODE == 0){
        const int proj = o >> 10, wi = o & 1023, hh = wi >> 6, dd = wi & 63;
        u16* base = (proj == 0) ? q_ws : ((proj == 1) ? k_ws : v_ws);
        #pragma unroll
        for (int r = 0; r < 4; r++){
          const size_t i = i0 + r;
          const size_t bb = i >> 11, nn = i & 2047;
          base[((bb*16 + hh)*2048 + nn)*64 + dd] = f2bf(acc[m][n][r] + bias_v);
        }
      } else {
        #pragma unroll
        for (int r = 0; r < 4; r++)
          Cout[(i0 + r)*1024 + o] = acc[m][n][r] + bias_v;
      }
    }
  }
}

// ---------------- flash attention: 64 q-rows/block, 4 waves x 16 rows ----------------
// Q,K,V: [b,h,n,64] bf16.  O: [b,n,h,64] bf16.
__global__ __launch_bounds__(256) void attn_k(
    const u16* __restrict__ Q, const u16* __restrict__ Kb, const u16* __restrict__ Vb,
    u16* __restrict__ O)
{
  __shared__ u16 Ks[32*64];
  __shared__ u16 Vs[32*64];
  const int tid = threadIdx.x, w = tid >> 6, lane = tid & 63;
  const int g = lane >> 4, q16 = lane & 15;
  const int qt = blockIdx.x, h = blockIdx.y, b = blockIdx.z;
  const size_t hb = ((size_t)(b*16 + h)) * 2048 * 64;
  const int qrow = qt*64 + w*16 + q16;

  // Q as B-operand fragments: col=lane&15 -> q row, k=dh (two K=32 chunks)
  bf16x8 qf[2];
  #pragma unroll
  for (int c = 0; c < 2; c++)
    qf[c] = __builtin_bit_cast(bf16x8, *(const uint4*)(Q + hb + (size_t)qrow*64 + c*32 + g*8));

  float mrun = -1e30f, lrun = 0.f;
  f32x4 acc[4] = {};   // out^T, 4 d-tiles of 16

  const int srow = lane >> 3, scol = (lane & 7) * 8;
  for (int j0 = 0; j0 < 2048; j0 += 32){
    __syncthreads();
    GLD_LDS16(Kb + hb + (size_t)(j0 + w*8 + srow)*64 + scol, Ks + w*512);
    GLD_LDS16(Vb + hb + (size_t)(j0 + w*8 + srow)*64 + scol, Vs + w*512);
    __syncthreads();

    // S^T = K * Q^T  (two 16-j tiles), C/D: col=q (lane&15), row=j_local=g*4+r
    f32x4 st0 = {}, st1 = {};
    #pragma unroll
    for (int c = 0; c < 2; c++){
      bf16x8 kf0 = __builtin_bit_cast(bf16x8, *(const uint4*)(Ks + q16*64      + c*32 + g*8));
      st0 = __builtin_amdgcn_mfma_f32_16x16x32_bf16(kf0, qf[c], st0, 0, 0, 0);
      bf16x8 kf1 = __builtin_bit_cast(bf16x8, *(const uint4*)(Ks + (16+q16)*64 + c*32 + g*8));
      st1 = __builtin_amdgcn_mfma_f32_16x16x32_bf16(kf1, qf[c], st1, 0, 0, 0);
    }

    float s[8];
    #pragma unroll
    for (int r = 0; r < 4; r++){ s[r] = st0[r]*INV_SCALE; s[4+r] = st1[r]*INV_SCALE; }
    float smax = s[0];
    #pragma unroll
    for (int i = 1; i < 8; i++) smax = fmaxf(smax, s[i]);
    smax = fmaxf(smax, __shfl_xor(smax, 16, 64));
    smax = fmaxf(smax, __shfl_xor(smax, 32, 64));
    const float mnew = fmaxf(mrun, smax);
    const float rs = __expf(mrun - mnew);
    float p[8], psum = 0.f;
    #pragma unroll
    for (int i = 0; i < 8; i++){ p[i] = __expf(s[i] - mnew); psum += p[i]; }
    psum += __shfl_xor(psum, 16, 64);
    psum += __shfl_xor(psum, 32, 64);
    lrun = lrun*rs + psum; mrun = mnew;

    // P^T as B-operand: col=q (lane&15) matches; k=j via bijection j(g,i)
    bf16x8 pf;
    #pragma unroll
    for (int i = 0; i < 8; i++) pf[i] = __builtin_bit_cast(__bf16, f2bf(p[i]));

    #pragma unroll
    for (int dt = 0; dt < 4; dt++){
      #pragma unroll
      for (int r = 0; r < 4; r++) acc[dt][r] *= rs;
      bf16x8 vf;  // V^T A-operand: row=d_local=lane&15, same j bijection
      #pragma unroll
      for (int i = 0; i < 8; i++){
        const int jl = (i < 4) ? (g*4 + i) : (16 + g*4 + (i - 4));
        vf[i] = __builtin_bit_cast(__bf16, Vs[jl*64 + dt*16 + q16]);
      }
      acc[dt] = __builtin_amdgcn_mfma_f32_16x16x32_bf16(vf, pf, acc[dt], 0, 0, 0);
    }
  }

  const float invl = 1.f / lrun;
  const size_t ob = ((size_t)(b*2048 + qt*64 + w*16 + q16)*16 + h)*64;
  #pragma unroll
  for (int dt = 0; dt < 4; dt++){
    union{ u16 u[4]; uint64_t v; } pk;
    #pragma unroll
    for (int r = 0; r < 4; r++) pk.u[r] = f2bf(acc[dt][r]*invl);
    *reinterpret_cast<uint64_t*>(O + ob + dt*16 + g*4) = pk.v;
  }
}

// ---------------- launch ----------------
extern "C" void kernel_launch(void* const* d_in, const int* in_sizes, int n_in,
                              void* d_out, int out_size, void* d_ws, size_t ws_size,
                              hipStream_t stream)
{
  const float* x  = (const float*)d_in[0];
  const float* Wq = (const float*)d_in[1];
  const float* bq = (const float*)d_in[2];
  const float* Wk = (const float*)d_in[3];
  const float* bk = (const float*)d_in[4];
  const float* Wv = (const float*)d_in[5];
  const float* bv = (const float*)d_in[6];
  const float* Wo = (const float*)d_in[7];
  const float* bo = (const float*)d_in[8];
  float* out = (float*)d_out;

  char* ws = (char*)d_ws;
  size_t off = 0;
  auto bump = [&](size_t bytes){ size_t o = off; off = (off + bytes + 255) & ~(size_t)255; return o; };
  u16*  xb   = (u16*)  (ws + bump(8388608ull*2));
  u16*  wqkv = (u16*)  (ws + bump(3145728ull*2));
  u16*  wob  = (u16*)  (ws + bump(1048576ull*2));
  float* bqkv= (float*)(ws + bump(3072ull*4));
  u16*  qws  = (u16*)  (ws + bump(8388608ull*2));
  u16*  kws  = (u16*)  (ws + bump(8388608ull*2));
  u16*  vws  = (u16*)  (ws + bump(8388608ull*2));
  u16*  att  = (u16*)  (ws + bump(8388608ull*2));

  k_cvt<<<1024, 256, 0, stream>>>((const float4*)x,  (uint64_t*)xb,           2097152);
  k_cvt<<<256,  256, 0, stream>>>((const float4*)Wq, (uint64_t*)wqkv,          262144);
  k_cvt<<<256,  256, 0, stream>>>((const float4*)Wk, (uint64_t*)(wqkv+1048576),262144);
  k_cvt<<<256,  256, 0, stream>>>((const float4*)Wv, (uint64_t*)(wqkv+2097152),262144);
  k_cvt<<<256,  256, 0, stream>>>((const float4*)Wo, (uint64_t*)wob,           262144);
  hipMemcpyAsync(bqkv,        bq, 4096, hipMemcpyDeviceToDevice, stream);
  hipMemcpyAsync(bqkv + 1024, bk, 4096, hipMemcpyDeviceToDevice, stream);
  hipMemcpyAsync(bqkv + 2048, bv, 4096, hipMemcpyDeviceToDevice, stream);

  gemm_bt<0><<<dim3(24, 64), 256, 0, stream>>>(xb, wqkv, bqkv, nullptr, qws, kws, vws);
  attn_k<<<dim3(32, 16, 4), 256, 0, stream>>>(qws, kws, vws, att);
  gemm_bt<1><<<dim3(8, 64), 256, 0, stream>>>(att, wob, bo, out, nullptr, nullptr, nullptr);
}

// Round 2
// 259.845 us; speedup vs baseline: 1.3573x; 1.3573x over previous
//
#include <hip/hip_runtime.h>
#include <stdint.h>

typedef unsigned short u16;
typedef __bf16 bf16x8 __attribute__((ext_vector_type(8)));
typedef float f32x4 __attribute__((ext_vector_type(4)));

// fold score scale (19.5/1024) and log2(e) into Q at projection time
#define QSCALE (19.5f/1024.0f * 1.44269504088896340736f)

__device__ __forceinline__ u16 f2bf(float f){
  uint32_t u = __float_as_uint(f);
  return (u16)((u + 0x7FFFu + ((u >> 16) & 1u)) >> 16);   // RNE
}

#define GLD_LDS16(g,l) __builtin_amdgcn_global_load_lds( \
    (const __attribute__((address_space(1))) void*)(g),  \
    (__attribute__((address_space(3))) void*)(l), 16, 0, 0)

// ---------------- fp32 -> bf16 convert (vectorized x4) ----------------
__global__ __launch_bounds__(256) void k_cvt(const float4* __restrict__ s,
                                             uint64_t* __restrict__ d, int n4){
  int i = blockIdx.x * 256 + threadIdx.x;
  const int stride = gridDim.x * 256;
  for (; i < n4; i += stride){
    float4 f = s[i];
    union{ u16 u[4]; uint64_t v; } pk;
    pk.u[0]=f2bf(f.x); pk.u[1]=f2bf(f.y); pk.u[2]=f2bf(f.z); pk.u[3]=f2bf(f.w);
    d[i] = pk.v;
  }
}

// ---------------- 128x128 bf16 GEMM: C = A[M][1024] * Bw[Nout][1024]^T + bias ----------------
// MODE 0: QKV projection -> Q (scaled, [b,h,n,dh]), K ([b,h,n,dh]), V^T ([b,h,dh,n])
// MODE 1: output projection -> fp32 C
template<int MODE>
__global__ __launch_bounds__(256) void gemm_bt(
    const u16* __restrict__ A, const u16* __restrict__ Bw,
    const float* __restrict__ bias, float* __restrict__ Cout,
    u16* __restrict__ q_ws, u16* __restrict__ k_ws, u16* __restrict__ v_ws)
{
  __shared__ u16 As[128*32];
  __shared__ u16 Bs[128*32];
  const int tid  = threadIdx.x;
  const int w    = tid >> 6, lane = tid & 63;
  const int wr   = w >> 1,  wc   = w & 1;
  const int g    = lane >> 4, c16 = lane & 15;
  const int nt   = blockIdx.x, mt = blockIdx.y;
  const size_t arow0 = (size_t)mt * 128, brow0 = (size_t)nt * 128;

  f32x4 acc[4][4] = {};

  const int srow = lane >> 2;          // row within 16-row chunk
  const int scol = (lane & 3) * 8;     // bf16-element offset within 32-wide row

  for (int k0 = 0; k0 < 1024; k0 += 32){
    __syncthreads();
    #pragma unroll
    for (int t = 0; t < 2; t++){
      const int c = w*2 + t;           // 8 chunks of 16 rows
      GLD_LDS16(A  + (arow0 + c*16 + srow)*1024 + k0 + scol, As + c*512);
      GLD_LDS16(Bw + (brow0 + c*16 + srow)*1024 + k0 + scol, Bs + c*512);
    }
    __syncthreads();

    bf16x8 af[4], bfr[4];
    #pragma unroll
    for (int m = 0; m < 4; m++)
      af[m]  = __builtin_bit_cast(bf16x8, *(const uint4*)(As + (wr*64 + m*16 + c16)*32 + g*8));
    #pragma unroll
    for (int n = 0; n < 4; n++)
      bfr[n] = __builtin_bit_cast(bf16x8, *(const uint4*)(Bs + (wc*64 + n*16 + c16)*32 + g*8));
    #pragma unroll
    for (int m = 0; m < 4; m++)
      #pragma unroll
      for (int n = 0; n < 4; n++)
        acc[m][n] = __builtin_amdgcn_mfma_f32_16x16x32_bf16(af[m], bfr[n], acc[m][n], 0, 0, 0);
  }

  #pragma unroll
  for (int m = 0; m < 4; m++){
    const size_t i0 = arow0 + wr*64 + m*16 + g*4;   // C/D: row=(lane>>4)*4+reg
    #pragma unroll
    for (int n = 0; n < 4; n++){
      const int o = (int)brow0 + wc*64 + n*16 + c16; // C/D: col=lane&15
      const float bias_v = bias[o];
      if (MODE == 0){
        const int proj = o >> 10, wi = o & 1023, hh = wi >> 6, dd = wi & 63;
        if (proj < 2){
          u16* base = (proj == 0) ? q_ws : k_ws;
          const float sc = (proj == 0) ? QSCALE : 1.0f;
          #pragma unroll
          for (int r = 0; r < 4; r++){
            const size_t i = i0 + r;
            const size_t bb = i >> 11, nn = i & 2047;
            base[((bb*16 + hh)*2048 + nn)*64 + dd] = f2bf((acc[m][n][r] + bias_v)*sc);
          }
        } else {
          // V^T: [b, h, dh(64), n(2048)]; i0 % 4 == 0 -> pack 4 consecutive n
          const size_t bb = i0 >> 11, nn = i0 & 2047;
          union{ u16 u[4]; uint64_t v; } pk;
          #pragma unroll
          for (int r = 0; r < 4; r++) pk.u[r] = f2bf(acc[m][n][r] + bias_v);
          *reinterpret_cast<uint64_t*>(v_ws + ((bb*16 + hh)*64 + dd)*2048 + nn) = pk.v;
        }
      } else {
        #pragma unroll
        for (int r = 0; r < 4; r++)
          Cout[(i0 + r)*1024 + o] = acc[m][n][r] + bias_v;
      }
    }
  }
}

// ---------------- flash attention: 64 q-rows/block, 4 waves x 16 rows, KVBLK=64 ----------------
// Q: [b,h,n,64] bf16 (pre-scaled by QSCALE). K: [b,h,n,64]. Vt: [b,h,64,n]. O: [b,n,h,64] bf16.
__global__ __launch_bounds__(256) void attn_k(
    const u16* __restrict__ Q, const u16* __restrict__ Kb, const u16* __restrict__ Vt,
    u16* __restrict__ O)
{
  __shared__ u16 Ks[2][64*64];   // swizzled: (row, slot) holds src cols (slot^ (row&7))*8..+7
  __shared__ u16 Vs[2][64*64];   // same swizzle, rows are d, cols are j
  const int tid = threadIdx.x, w = tid >> 6, lane = tid & 63;
  const int g = lane >> 4, q16 = lane & 15;

  // XCD swizzle: 2048 blocks, 8 XCDs -> each XCD owns 8 (b,h) pairs (4MB K+V in its L2)
  const int f  = ((blockIdx.x & 7) << 8) | (blockIdx.x >> 3);
  const int qt = f & 31, h = (f >> 5) & 15, b = f >> 9;
  const size_t hb = ((size_t)(b*16 + h)) * 2048 * 64;
  const int qrow = qt*64 + w*16 + q16;

  // Q as B-operand fragments: col=lane&15 -> q row, k=dh (two K=32 chunks)
  bf16x8 qf[2];
  #pragma unroll
  for (int c = 0; c < 2; c++)
    qf[c] = __builtin_bit_cast(bf16x8, *(const uint4*)(Q + hb + (size_t)qrow*64 + c*32 + g*8));

  float mrun = -1e30f, lrun = 0.f;
  f32x4 acc[4] = {};   // out^T, 4 d-tiles of 16

  const int srow = lane >> 3;                 // row within 8-row chunk (also row&7)
  const int ssl  = ((lane & 7) ^ srow) * 8;   // pre-swizzled source slot (u16 units)

  // stage tile [64 rows][64 cols] into buf; K rows = j, Vt rows = d
  auto stage = [&](int buf, int j0){
    #pragma unroll
    for (int rd = 0; rd < 2; rd++){
      const int row = rd*32 + w*8 + srow;
      GLD_LDS16(Kb + hb + (size_t)(j0 + row)*64 + ssl, &Ks[buf][rd*2048 + w*512]);
      GLD_LDS16(Vt + hb + (size_t)row*2048 + j0 + ssl, &Vs[buf][rd*2048 + w*512]);
    }
  };

  stage(0, 0);
  __syncthreads();
  int cur = 0;

  for (int jt = 0; jt < 32; jt++){
    if (jt < 31) stage(cur ^ 1, (jt + 1)*64);
    const u16* K_ = Ks[cur];
    const u16* V_ = Vs[cur];

    // S^T tiles: st[t] covers j = jt*64 + t*16 + (g*4+r), col = q (lane&15)
    f32x4 st[4] = {{0,0,0,0},{0,0,0,0},{0,0,0,0},{0,0,0,0}};
    #pragma unroll
    for (int c = 0; c < 2; c++){
      #pragma unroll
      for (int t = 0; t < 4; t++){
        const int row = t*16 + q16;
        bf16x8 kf = __builtin_bit_cast(bf16x8,
            *(const uint4*)(K_ + row*64 + (((c*4 + g) ^ (q16 & 7)) << 3)));
        st[t] = __builtin_amdgcn_mfma_f32_16x16x32_bf16(kf, qf[c], st[t], 0, 0, 0);
      }
    }

    // softmax (log2 domain; scale folded into Q)
    float smax = st[0][0];
    #pragma unroll
    for (int t = 0; t < 4; t++)
      #pragma unroll
      for (int r = 0; r < 4; r++) smax = fmaxf(smax, st[t][r]);
    smax = fmaxf(smax, __shfl_xor(smax, 16, 64));
    smax = fmaxf(smax, __shfl_xor(smax, 32, 64));

    if (__any(smax > mrun + 8.f)){            // defer-max (T13), THR=8 in log2 domain
      const float mnew = fmaxf(mrun, smax);
      const float rs = __builtin_amdgcn_exp2f(mrun - mnew);
      lrun *= rs;
      #pragma unroll
      for (int dt = 0; dt < 4; dt++)
        #pragma unroll
        for (int r = 0; r < 4; r++) acc[dt][r] *= rs;
      mrun = mnew;
    }

    float p[16], psum = 0.f;
    #pragma unroll
    for (int t = 0; t < 4; t++)
      #pragma unroll
      for (int r = 0; r < 4; r++){
        p[t*4+r] = __builtin_amdgcn_exp2f(st[t][r] - mrun);
        psum += p[t*4+r];
      }
    psum += __shfl_xor(psum, 16, 64);
    psum += __shfl_xor(psum, 32, 64);
    lrun += psum;

    // PV: out^T[d][q] += V^T[d][j] * P^T[j][q], j-bijection (g,i,c): c*32+half*16+g*4+(i&3)
    #pragma unroll
    for (int c = 0; c < 2; c++){
      bf16x8 pf;
      #pragma unroll
      for (int i = 0; i < 8; i++) pf[i] = (__bf16)p[c*8 + i];
      #pragma unroll
      for (int dt = 0; dt < 4; dt++){
        const int row = dt*16 + q16;
        union { uint64_t v[2]; bf16x8 f; } vf;
        const int s0 = (((c*4 + 0 + (g>>1)) ^ (q16 & 7)) << 3) + (g & 1)*4;
        const int s1 = (((c*4 + 2 + (g>>1)) ^ (q16 & 7)) << 3) + (g & 1)*4;
        vf.v[0] = *(const uint64_t*)(V_ + row*64 + s0);
        vf.v[1] = *(const uint64_t*)(V_ + row*64 + s1);
        acc[dt] = __builtin_amdgcn_mfma_f32_16x16x32_bf16(vf.f, pf, acc[dt], 0, 0, 0);
      }
    }
    __syncthreads();
    cur ^= 1;
  }

  const float invl = 1.f / lrun;
  const size_t ob = ((size_t)(b*2048 + qt*64 + w*16 + q16)*16 + h)*64;
  #pragma unroll
  for (int dt = 0; dt < 4; dt++){
    union{ u16 u[4]; uint64_t v; } pk;
    #pragma unroll
    for (int r = 0; r < 4; r++) pk.u[r] = f2bf(acc[dt][r]*invl);
    *reinterpret_cast<uint64_t*>(O + ob + dt*16 + g*4) = pk.v;
  }
}

// ---------------- launch ----------------
extern "C" void kernel_launch(void* const* d_in, const int* in_sizes, int n_in,
                              void* d_out, int out_size, void* d_ws, size_t ws_size,
                              hipStream_t stream)
{
  const float* x  = (const float*)d_in[0];
  const float* Wq = (const float*)d_in[1];
  const float* bq = (const float*)d_in[2];
  const float* Wk = (const float*)d_in[3];
  const float* bk = (const float*)d_in[4];
  const float* Wv = (const float*)d_in[5];
  const float* bv = (const float*)d_in[6];
  const float* Wo = (const float*)d_in[7];
  const float* bo = (const float*)d_in[8];
  float* out = (float*)d_out;

  char* ws = (char*)d_ws;
  size_t off = 0;
  auto bump = [&](size_t bytes){ size_t o = off; off = (off + bytes + 255) & ~(size_t)255; return o; };
  u16*  xb   = (u16*)  (ws + bump(8388608ull*2));
  u16*  wqkv = (u16*)  (ws + bump(3145728ull*2));
  u16*  wob  = (u16*)  (ws + bump(1048576ull*2));
  float* bqkv= (float*)(ws + bump(3072ull*4));
  u16*  qws  = (u16*)  (ws + bump(8388608ull*2));
  u16*  kws  = (u16*)  (ws + bump(8388608ull*2));
  u16*  vws  = (u16*)  (ws + bump(8388608ull*2));
  u16*  att  = (u16*)  (ws + bump(8388608ull*2));

  k_cvt<<<1024, 256, 0, stream>>>((const float4*)x,  (uint64_t*)xb,           2097152);
  k_cvt<<<256,  256, 0, stream>>>((const float4*)Wq, (uint64_t*)wqkv,          262144);
  k_cvt<<<256,  256, 0, stream>>>((const float4*)Wk, (uint64_t*)(wqkv+1048576),262144);
  k_cvt<<<256,  256, 0, stream>>>((const float4*)Wv, (uint64_t*)(wqkv+2097152),262144);
  k_cvt<<<256,  256, 0, stream>>>((const float4*)Wo, (uint64_t*)wob,           262144);
  hipMemcpyAsync(bqkv,        bq, 4096, hipMemcpyDeviceToDevice, stream);
  hipMemcpyAsync(bqkv + 1024, bk, 4096, hipMemcpyDeviceToDevice, stream);
  hipMemcpyAsync(bqkv + 2048, bv, 4096, hipMemcpyDeviceToDevice, stream);

  gemm_bt<0><<<dim3(24, 64), 256, 0, stream>>>(xb, wqkv, bqkv, nullptr, qws, kws, vws);
  attn_k<<<2048, 256, 0, stream>>>(qws, kws, vws, att);
  gemm_bt<1><<<dim3(8, 64), 256, 0, stream>>>(att, wob, bo, out, nullptr, nullptr, nullptr);
}